// Round 6
// baseline (22.184 us; speedup 1.0000x reference)
//
#include <hip/hip_runtime.h>

namespace {

typedef unsigned short ushort_t;
typedef unsigned int uint_t;
typedef __attribute__((ext_vector_type(8))) short short8v;   // 8 bf16 (4 VGPRs)
typedef __attribute__((ext_vector_type(4))) float f32x4;     // MFMA accumulator

constexpr int kB = 8, kN = 256, kF = 128, kH = 128, kO = 64;
constexpr int kR = 4;              // real rows per block (padded to 16 for MFMA)
constexpr int kTPB = 512;          // 8 waves
constexpr int kOut0 = kB * kN * kO;

// d_ws frag-slot bases (each slot = 64 lanes x 16B = 1KB, holds one B-frag)
constexpr int FW_WHH  = 0;     // w_hh : 24 tiles x 4 kf  = 96
constexpr int FW_FCW  = 96;    // fc_w :  8 tiles x 12 kf = 96
constexpr int FW_WIH  = 192;   // w_ih : 24 tiles x 4 kf  = 96
constexpr int FW_OUTW = 288;   // out_w:  4 tiles x 4 kf  = 16
constexpr int FW_GX   = 304;   // gx   :  8 b x 8 tiles x 8 kf = 512
constexpr int FW_TOTAL = 816;  // 816 KB total in d_ws

union Frag {
    uint_t  u[4];
    short8v v;
};

__device__ __forceinline__ float waveReduceAdd(float v) {
    v += __shfl_xor(v, 1);
    v += __shfl_xor(v, 2);
    v += __shfl_xor(v, 4);
    v += __shfl_xor(v, 8);
    v += __shfl_xor(v, 16);
    v += __shfl_xor(v, 32);
    return v;
}

__device__ __forceinline__ ushort_t cvt1(float f) {
    return (ushort_t)((__float_as_uint(f) + 0x8000u) >> 16);
}
__device__ __forceinline__ uint_t pk(float f0, float f1) {
    uint_t b0 = __float_as_uint(f0) + 0x8000u;
    uint_t b1 = __float_as_uint(f1) + 0x8000u;
    return (b1 & 0xFFFF0000u) | (b0 >> 16);
}
__device__ __forceinline__ float b2f(ushort_t h) {
    return __uint_as_float(((uint_t)h) << 16);
}
__device__ __forceinline__ void loadWFrag(const float* __restrict__ p, Frag& b) {
    float4 lo = *(const float4*)p;
    float4 hi = *(const float4*)(p + 4);
    b.u[0] = pk(lo.x, lo.y);
    b.u[1] = pk(lo.z, lo.w);
    b.u[2] = pk(hi.x, hi.y);
    b.u[3] = pk(hi.z, hi.w);
}

// ---------------- pre-pass: build bf16 B-frags in d_ws ----------------
__global__ __launch_bounds__(256) void convert_frags(
    const float* __restrict__ gx, const float* __restrict__ fc_w,
    const float* __restrict__ w_ih, const float* __restrict__ w_hh,
    const float* __restrict__ out_w, uint4* __restrict__ ws)
{
    const int gw = (int)((blockIdx.x * 256 + threadIdx.x) >> 6);
    if (gw >= FW_TOTAL) return;
    const int lane = threadIdx.x & 63;
    const int arow = lane & 15;
    const int kgrp = (lane >> 4) * 8;
    Frag fr;
    if (gw < FW_FCW) {                       // w_hh
        int idx = gw - FW_WHH, t = idx >> 2, kf = idx & 3;
        loadWFrag(w_hh + (size_t)(t * 16 + arow) * kH + kf * 32 + kgrp, fr);
    } else if (gw < FW_WIH) {                // fc_w
        int idx = gw - FW_FCW, t = idx / 12, kf = idx % 12;
        loadWFrag(fc_w + (size_t)(t * 16 + arow) * 384 + kf * 32 + kgrp, fr);
    } else if (gw < FW_OUTW) {               // w_ih
        int idx = gw - FW_WIH, t = idx >> 2, kf = idx & 3;
        loadWFrag(w_ih + (size_t)(t * 16 + arow) * kH + kf * 32 + kgrp, fr);
    } else if (gw < FW_GX) {                 // out_w
        int idx = gw - FW_OUTW, t = idx >> 2, kf = idx & 3;
        loadWFrag(out_w + (size_t)(t * 16 + arow) * kH + kf * 32 + kgrp, fr);
    } else {                                 // gx weak-phase B-frags
        int idx = gw - FW_GX;
        int bb = idx >> 6, rem = idx & 63, t = rem >> 3, kf = rem & 7;
        int k0 = kf * 32 + kgrp;
        const float* gp = gx + ((size_t)bb * kN + k0) * kF + t * 16 + arow;
        fr.u[0] = pk(gp[0 * kF], gp[1 * kF]);
        fr.u[1] = pk(gp[2 * kF], gp[3 * kF]);
        fr.u[2] = pk(gp[4 * kF], gp[5 * kF]);
        fr.u[3] = pk(gp[6 * kF], gp[7 * kF]);
    }
    ws[(size_t)gw * 64 + lane] = *(uint4*)fr.u;
}

// ---------------- fused main kernel: 4 rows/block, 2 blocks/CU ----------------
__global__ __launch_bounds__(kTPB, 4) void weak_tie_fused(
    const float* __restrict__ lx, const float* __restrict__ gx,
    const float* __restrict__ mask, const int* __restrict__ key_idx,
    const float* __restrict__ hstate,
    const float* __restrict__ fc_b,
    const float* __restrict__ ln_g, const float* __restrict__ ln_b,
    const float* __restrict__ b_ih, const float* __restrict__ b_hh,
    const float* __restrict__ out_b,
    const uint4* __restrict__ ws,
    float* __restrict__ out)
{
    // rows >= kR of the 16-row A-tiles are uninitialized garbage — their MFMA
    // C-rows are discarded (row < kR guard), so no zero-padding is needed.
    __shared__ __align__(16) ushort_t maskb[16][264];
    __shared__ __align__(16) ushort_t cmb[16][392];
    __shared__ __align__(16) ushort_t hf16[16][136];
    __shared__ __align__(16) ushort_t xb16[16][136];
    __shared__ __align__(16) ushort_t hnb16[16][136];
    __shared__ __align__(16) float hf32[kR * kH];
    __shared__ __align__(16) float hb[kR * kH];
    __shared__ __align__(16) ushort_t ghb[kR][384];
    __shared__ __align__(16) ushort_t gib[kR][384];
    __shared__ float denomInv[kR];

    const int tid  = threadIdx.x;
    const int b    = blockIdx.x >> 6;          // 64 row-tiles per batch
    const int row0 = (blockIdx.x & 63) * kR;
    const int lane = tid & 63;
    const int wv   = tid >> 6;                 // 0..7
    const int arow = lane & 15;
    const int kgrp = (lane >> 4) * 8;

    // ---------------- staging (512 threads cover r<4, c<128) ----------------
    {
        const int r = tid >> 7, c = tid & 127;
        const float* mrow = mask + ((size_t)b * kN + row0) * kN;
        maskb[r][c]       = cvt1(mrow[r * 256 + c]);
        maskb[r][c + 128] = cvt1(mrow[r * 256 + c + 128]);
        const float* lrow = lx + ((size_t)b * kN + row0) * kF;
        cmb[r][c] = cvt1(lrow[tid]);
        const int ki = key_idx[b];
        cmb[r][256 + c] = cvt1(gx[((size_t)b * kN + ki) * kF + c]);
        const float* hrow = hstate + ((size_t)b * kN + row0) * kH;
        float hv = hrow[tid];
        hf32[tid] = hv;
        hf16[r][c] = cvt1(hv);
    }
    __syncthreads();

    // ---------------- denom (waves 0..3, one row each) ----------------
    if (wv < kR) {
        int r = wv;
        float s = b2f(maskb[r][lane])       + b2f(maskb[r][lane + 64]) +
                  b2f(maskb[r][lane + 128]) + b2f(maskb[r][lane + 192]);
        s = waveReduceAdd(s);
        if (lane == 0) denomInv[r] = 1.0f / (s + 1e-6f);
    }
    __syncthreads();

    // ---------------- P1: weak (waves 0-3, 2 tiles each) || gh (waves 4-7, 6 tiles each) ----------------
    if (wv < 4) {
        Frag am[8];
        #pragma unroll
        for (int kf = 0; kf < 8; ++kf)
            *(uint4*)am[kf].u = *(const uint4*)&maskb[arow][kf * 32 + kgrp];
        #pragma unroll
        for (int tt = 0; tt < 2; ++tt) {
            const int t = wv * 2 + tt;
            const uint4* wsf = ws + ((size_t)(FW_GX + b * 64 + t * 8) * 64 + lane);
            f32x4 acc = {0.f, 0.f, 0.f, 0.f};
            #pragma unroll
            for (int kf = 0; kf < 8; ++kf) {
                Frag bb;
                *(uint4*)bb.u = wsf[(size_t)kf * 64];
                acc = __builtin_amdgcn_mfma_f32_16x16x32_bf16(am[kf].v, bb.v, acc, 0, 0, 0);
            }
            const int n0 = 16 * t;
            if ((lane >> 4) == 0) {          // rows 0..3 live in lanes 0..15
                #pragma unroll
                for (int j = 0; j < 4; ++j)
                    cmb[j][128 + n0 + arow] = cvt1(acc[j] * denomInv[j]);
            }
        }
    } else {
        Frag af[4];
        #pragma unroll
        for (int kf = 0; kf < 4; ++kf)
            *(uint4*)af[kf].u = *(const uint4*)&hf16[arow][kf * 32 + kgrp];
        #pragma unroll
        for (int t6 = 0; t6 < 6; ++t6) {
            const int tile = (wv - 4) * 6 + t6;
            const uint4* wsf = ws + ((size_t)(FW_WHH + tile * 4) * 64 + lane);
            f32x4 acc = {0.f, 0.f, 0.f, 0.f};
            #pragma unroll
            for (int kf = 0; kf < 4; ++kf) {
                Frag bb;
                *(uint4*)bb.u = wsf[(size_t)kf * 64];
                acc = __builtin_amdgcn_mfma_f32_16x16x32_bf16(af[kf].v, bb.v, acc, 0, 0, 0);
            }
            const int n0 = 16 * tile;
            if ((lane >> 4) == 0) {
                #pragma unroll
                for (int j = 0; j < 4; ++j)
                    ghb[j][n0 + arow] = cvt1(acc[j]);
            }
        }
    }
    __syncthreads();

    // ---------------- P2: FC (waves 0-3, 2 tiles each) || gi preload 3 tiles (waves 4-7) ----------------
    Frag bfr[12];    // waves 4-7: first 3 gi tiles' B-frags, held across barriers
    if (wv < 4) {
        Frag ac[12];
        #pragma unroll
        for (int kf = 0; kf < 12; ++kf)
            *(uint4*)ac[kf].u = *(const uint4*)&cmb[arow][kf * 32 + kgrp];
        #pragma unroll
        for (int tt = 0; tt < 2; ++tt) {
            const int t = wv * 2 + tt;
            const uint4* wsf = ws + ((size_t)(FW_FCW + t * 12) * 64 + lane);
            f32x4 acc = {0.f, 0.f, 0.f, 0.f};
            #pragma unroll
            for (int kf = 0; kf < 12; ++kf) {
                Frag bb;
                *(uint4*)bb.u = wsf[(size_t)kf * 64];
                acc = __builtin_amdgcn_mfma_f32_16x16x32_bf16(ac[kf].v, bb.v, acc, 0, 0, 0);
            }
            const int n0 = 16 * t;
            if ((lane >> 4) == 0) {
                #pragma unroll
                for (int j = 0; j < 4; ++j)
                    hb[j * 128 + n0 + arow] = acc[j];
            }
        }
    } else {
        #pragma unroll
        for (int t3 = 0; t3 < 3; ++t3) {
            const int tile = (wv - 4) * 6 + t3;
            const uint4* wsf = ws + ((size_t)(FW_WIH + tile * 4) * 64 + lane);
            #pragma unroll
            for (int kf = 0; kf < 4; ++kf)
                *(uint4*)bfr[t3 * 4 + kf].u = wsf[(size_t)kf * 64];
        }
    }
    __syncthreads();

    // ---------------- P3: LayerNorm + ReLU (waves 0-3, one row each) ----------------
    if (wv < kR) {
        int r = wv;
        float v0 = hb[r * 128 + lane]      + fc_b[lane];
        float v1 = hb[r * 128 + lane + 64] + fc_b[lane + 64];
        float s  = waveReduceAdd(v0 + v1);
        float ss = waveReduceAdd(v0 * v0 + v1 * v1);
        float mu   = s * (1.0f / 128.0f);
        float var  = ss * (1.0f / 128.0f) - mu * mu;
        float rstd = rsqrtf(var + 1e-5f);
        float x0 = fmaxf((v0 - mu) * rstd * ln_g[lane] + ln_b[lane], 0.f);
        float x1 = fmaxf((v1 - mu) * rstd * ln_g[lane + 64] + ln_b[lane + 64], 0.f);
        xb16[r][lane]      = cvt1(x0);
        xb16[r][lane + 64] = cvt1(x1);
    }
    __syncthreads();

    // ---------------- P4: gi (waves 4-7, 6 tiles: 3 preloaded + 3 inline) || out_w preload (waves 0-3) ----------------
    Frag obf[4];
    if (wv >= 4) {
        Frag af[4];
        #pragma unroll
        for (int kf = 0; kf < 4; ++kf)
            *(uint4*)af[kf].u = *(const uint4*)&xb16[arow][kf * 32 + kgrp];
        #pragma unroll
        for (int t6 = 0; t6 < 6; ++t6) {
            const int tile = (wv - 4) * 6 + t6;
            f32x4 acc = {0.f, 0.f, 0.f, 0.f};
            if (t6 < 3) {
                #pragma unroll
                for (int kf = 0; kf < 4; ++kf)
                    acc = __builtin_amdgcn_mfma_f32_16x16x32_bf16(af[kf].v, bfr[t6 * 4 + kf].v, acc, 0, 0, 0);
            } else {
                const uint4* wsf = ws + ((size_t)(FW_WIH + tile * 4) * 64 + lane);
                #pragma unroll
                for (int kf = 0; kf < 4; ++kf) {
                    Frag bb;
                    *(uint4*)bb.u = wsf[(size_t)kf * 64];
                    acc = __builtin_amdgcn_mfma_f32_16x16x32_bf16(af[kf].v, bb.v, acc, 0, 0, 0);
                }
            }
            const int n0 = 16 * tile;
            if ((lane >> 4) == 0) {
                #pragma unroll
                for (int j = 0; j < 4; ++j)
                    gib[j][n0 + arow] = cvt1(acc[j]);
            }
        }
    } else {
        const uint4* wsf = ws + ((size_t)(FW_OUTW + wv * 4) * 64 + lane);
        #pragma unroll
        for (int kf = 0; kf < 4; ++kf)
            *(uint4*)obf[kf].u = wsf[(size_t)kf * 64];
    }
    __syncthreads();

    // ---------------- P5: gate combine (512 threads = 4 rows x 128 cols) ----------------
    {
        const int r = tid >> 7, fcol = tid & 127;
        float ir  = b2f(gib[r][fcol])       + b_ih[fcol];
        float iz  = b2f(gib[r][128 + fcol]) + b_ih[128 + fcol];
        float inn = b2f(gib[r][256 + fcol]) + b_ih[256 + fcol];
        float hr  = b2f(ghb[r][fcol])       + b_hh[fcol];
        float hz  = b2f(ghb[r][128 + fcol]) + b_hh[128 + fcol];
        float hn  = b2f(ghb[r][256 + fcol]) + b_hh[256 + fcol];
        float rg = 1.0f / (1.0f + __expf(-(ir + hr)));
        float zg = 1.0f / (1.0f + __expf(-(iz + hz)));
        float ng = tanhf(inn + rg * hn);
        float hprev = hf32[r * 128 + fcol];
        float hnew = (1.0f - zg) * ng + zg * hprev;
        hnb16[r][fcol] = cvt1(hnew);
        out[kOut0 + ((size_t)(b * kN + row0 + r)) * kH + fcol] = hnew;
    }
    __syncthreads();

    // ---------------- P6: out head (waves 0-3, one 16-col tile each) ----------------
    if (wv < 4) {
        const int n0 = 16 * wv;
        Frag af[4];
        #pragma unroll
        for (int kf = 0; kf < 4; ++kf)
            *(uint4*)af[kf].u = *(const uint4*)&hnb16[arow][kf * 32 + kgrp];
        f32x4 acc = {0.f, 0.f, 0.f, 0.f};
        #pragma unroll
        for (int kf = 0; kf < 4; ++kf)
            acc = __builtin_amdgcn_mfma_f32_16x16x32_bf16(af[kf].v, obf[kf].v, acc, 0, 0, 0);
        if ((lane >> 4) == 0) {
            float ob = out_b[n0 + arow];
            #pragma unroll
            for (int j = 0; j < 4; ++j)
                out[((size_t)(b * kN + row0 + j)) * kO + n0 + arow] = acc[j] + ob;
        }
    }
}

} // namespace

extern "C" void kernel_launch(void* const* d_in, const int* in_sizes, int n_in,
                              void* d_out, int out_size, void* d_ws, size_t ws_size,
                              hipStream_t stream) {
    const float* lx      = (const float*)d_in[0];
    const float* gx      = (const float*)d_in[1];
    const float* mask    = (const float*)d_in[2];
    const int*   key_idx = (const int*)  d_in[3];
    const float* hs      = (const float*)d_in[4];
    const float* fc_w    = (const float*)d_in[5];
    const float* fc_b    = (const float*)d_in[6];
    const float* ln_g    = (const float*)d_in[7];
    const float* ln_b    = (const float*)d_in[8];
    const float* w_ih    = (const float*)d_in[9];
    const float* w_hh    = (const float*)d_in[10];
    const float* b_ih    = (const float*)d_in[11];
    const float* b_hh    = (const float*)d_in[12];
    const float* out_w   = (const float*)d_in[13];
    const float* out_b   = (const float*)d_in[14];
    float* out = (float*)d_out;
    uint4* ws = (uint4*)d_ws;   // needs 816 KB

    hipLaunchKernelGGL(convert_frags, dim3((FW_TOTAL * 64) / 256), dim3(256), 0, stream,
                       gx, fc_w, w_ih, w_hh, out_w, ws);

    dim3 grid(kB * kN / kR);   // 512 blocks -> 2 per CU
    dim3 block(kTPB);          // 512 threads = 8 waves
    hipLaunchKernelGGL(weak_tie_fused, grid, block, 0, stream,
                       lx, gx, mask, key_idx, hs,
                       fc_b, ln_g, ln_b,
                       b_ih, b_hh, out_b,
                       (const uint4*)ws, out);
}

// Round 7
// 18.433 us; speedup vs baseline: 1.2035x; 1.2035x over previous
//
#include <hip/hip_runtime.h>

namespace {

typedef unsigned short ushort_t;
typedef unsigned int uint_t;
typedef __attribute__((ext_vector_type(8))) short short8v;   // 8 bf16 (4 VGPRs)
typedef __attribute__((ext_vector_type(4))) float f32x4;     // MFMA accumulator

constexpr int kB = 8, kN = 256, kF = 128, kH = 128, kO = 64;
constexpr int kR = 8;              // real rows per block (16-row MFMA tiles, rows 8-15 garbage/discarded)
constexpr int kTPB = 1024;         // 16 waves
constexpr int kOut0 = kB * kN * kO;

// d_ws frag-slot bases (each slot = 64 lanes x 16B = 1KB, holds one B-frag)
constexpr int FW_WHH  = 0;     // w_hh : 24 tiles x 4 kf  = 96
constexpr int FW_FCW  = 96;    // fc_w :  8 tiles x 12 kf = 96
constexpr int FW_WIH  = 192;   // w_ih : 24 tiles x 4 kf  = 96
constexpr int FW_OUTW = 288;   // out_w:  4 tiles x 4 kf  = 16
constexpr int FW_GX   = 304;   // gx   :  8 b x 8 tiles x 8 kf = 512
constexpr int FW_TOTAL = 816;  // 816 KB total in d_ws

union Frag {
    uint_t  u[4];
    short8v v;
};

__device__ __forceinline__ float waveReduceAdd(float v) {
    v += __shfl_xor(v, 1);
    v += __shfl_xor(v, 2);
    v += __shfl_xor(v, 4);
    v += __shfl_xor(v, 8);
    v += __shfl_xor(v, 16);
    v += __shfl_xor(v, 32);
    return v;
}

__device__ __forceinline__ ushort_t cvt1(float f) {
    return (ushort_t)((__float_as_uint(f) + 0x8000u) >> 16);
}
__device__ __forceinline__ uint_t pk(float f0, float f1) {
    uint_t b0 = __float_as_uint(f0) + 0x8000u;
    uint_t b1 = __float_as_uint(f1) + 0x8000u;
    return (b1 & 0xFFFF0000u) | (b0 >> 16);
}
__device__ __forceinline__ float sigm(float x) {
    return __builtin_amdgcn_rcpf(1.0f + __expf(-x));
}
__device__ __forceinline__ float tanh_fast(float x) {
    x = fminf(fmaxf(x, -15.0f), 15.0f);
    float e = __expf(2.0f * x);
    return (e - 1.0f) * __builtin_amdgcn_rcpf(e + 1.0f);
}
__device__ __forceinline__ void loadWFrag(const float* __restrict__ p, Frag& b) {
    float4 lo = *(const float4*)p;
    float4 hi = *(const float4*)(p + 4);
    b.u[0] = pk(lo.x, lo.y);
    b.u[1] = pk(lo.z, lo.w);
    b.u[2] = pk(hi.x, hi.y);
    b.u[3] = pk(hi.z, hi.w);
}

// ---------------- pre-pass: build bf16 B-frags in d_ws ----------------
__global__ __launch_bounds__(256) void convert_frags(
    const float* __restrict__ gx, const float* __restrict__ fc_w,
    const float* __restrict__ w_ih, const float* __restrict__ w_hh,
    const float* __restrict__ out_w, uint4* __restrict__ ws)
{
    const int gw = (int)((blockIdx.x * 256 + threadIdx.x) >> 6);
    if (gw >= FW_TOTAL) return;
    const int lane = threadIdx.x & 63;
    const int arow = lane & 15;
    const int kgrp = (lane >> 4) * 8;
    Frag fr;
    if (gw < FW_FCW) {                       // w_hh
        int idx = gw - FW_WHH, t = idx >> 2, kf = idx & 3;
        loadWFrag(w_hh + (size_t)(t * 16 + arow) * kH + kf * 32 + kgrp, fr);
    } else if (gw < FW_WIH) {                // fc_w
        int idx = gw - FW_FCW, t = idx / 12, kf = idx % 12;
        loadWFrag(fc_w + (size_t)(t * 16 + arow) * 384 + kf * 32 + kgrp, fr);
    } else if (gw < FW_OUTW) {               // w_ih
        int idx = gw - FW_WIH, t = idx >> 2, kf = idx & 3;
        loadWFrag(w_ih + (size_t)(t * 16 + arow) * kH + kf * 32 + kgrp, fr);
    } else if (gw < FW_GX) {                 // out_w
        int idx = gw - FW_OUTW, t = idx >> 2, kf = idx & 3;
        loadWFrag(out_w + (size_t)(t * 16 + arow) * kH + kf * 32 + kgrp, fr);
    } else {                                 // gx weak-phase B-frags
        int idx = gw - FW_GX;
        int bb = idx >> 6, rem = idx & 63, t = rem >> 3, kf = rem & 7;
        int k0 = kf * 32 + kgrp;
        const float* gp = gx + ((size_t)bb * kN + k0) * kF + t * 16 + arow;
        fr.u[0] = pk(gp[0 * kF], gp[1 * kF]);
        fr.u[1] = pk(gp[2 * kF], gp[3 * kF]);
        fr.u[2] = pk(gp[4 * kF], gp[5 * kF]);
        fr.u[3] = pk(gp[6 * kF], gp[7 * kF]);
    }
    ws[(size_t)gw * 64 + lane] = *(uint4*)fr.u;
}

#define MFMA16(A, B, C) __builtin_amdgcn_mfma_f32_16x16x32_bf16((A), (B), (C), 0, 0, 0)

// ---------------- fused main kernel: 8 rows/block, 256 blocks, 5 barriers ----------------
__global__ __launch_bounds__(kTPB, 4) void weak_tie_fused(
    const float* __restrict__ lx, const float* __restrict__ gx,
    const float* __restrict__ mask, const int* __restrict__ key_idx,
    const float* __restrict__ hstate,
    const float* __restrict__ fc_b,
    const float* __restrict__ ln_g, const float* __restrict__ ln_b,
    const float* __restrict__ b_ih, const float* __restrict__ b_hh,
    const float* __restrict__ out_b,
    const uint4* __restrict__ ws,
    float* __restrict__ out)
{
    // rows 8-15 of the 16-row A-tiles are garbage; their C-rows are discarded (lane<32 guards).
    __shared__ __align__(16) ushort_t maskb[16][264];
    __shared__ __align__(16) ushort_t cmb[16][392];
    __shared__ __align__(16) ushort_t hf16[16][136];
    __shared__ __align__(16) ushort_t xb16[16][136];
    __shared__ __align__(16) ushort_t hnb16[16][136];
    __shared__ __align__(16) float hf32[kR * kH];
    __shared__ __align__(16) float hb[kR * kH];
    __shared__ float denomInv[kR];

    const int tid  = threadIdx.x;
    const int b    = blockIdx.x >> 5;
    const int row0 = (blockIdx.x & 31) * kR;
    const int lane = tid & 63;
    const int wv   = tid >> 6;            // 0..15
    const int arow = lane & 15;
    const int kgrp = (lane >> 4) * 8;

    // ================ S: stage + denom + weak-frag prefetch ================
    Frag wkf[8];                           // waves 0-7: weak B-frags (live S->P1)
    if (wv < 8) {
        const uint4* wsf = ws + ((size_t)(FW_GX + b * 64 + wv * 8) * 64 + lane);
        #pragma unroll
        for (int kf = 0; kf < 8; ++kf) *(uint4*)wkf[kf].u = wsf[(size_t)kf * 64];
    }
    {
        const int r = tid >> 7, c = tid & 127;
        const float* mrow = mask + ((size_t)b * kN + row0) * kN;
        maskb[r][c]       = cvt1(mrow[r * 256 + c]);
        maskb[r][c + 128] = cvt1(mrow[r * 256 + c + 128]);
        cmb[r][c] = cvt1(lx[((size_t)b * kN + row0) * kF + tid]);
        const int ki = key_idx[b];
        cmb[r][256 + c] = cvt1(gx[((size_t)b * kN + ki) * kF + c]);
        float hv = hstate[((size_t)b * kN + row0) * kH + tid];
        hf32[tid] = hv;
        hf16[r][c] = cvt1(hv);
    }
    if (wv < 8) {                          // denom in fp32 straight from global
        const float* mr = mask + ((size_t)b * kN + row0 + wv) * kN;
        float4 m4 = *(const float4*)(mr + lane * 4);
        float s = waveReduceAdd(m4.x + m4.y + m4.z + m4.w);
        if (lane == 0) denomInv[wv] = 1.0f / (s + 1e-6f);
    }
    __syncthreads();

    // ================ P1: weak (waves 0-7) || gh->regs (waves 8-15) ================
    f32x4 gh0 = {0.f, 0.f, 0.f, 0.f}, gh1 = gh0, gh2 = gh0;   // waves 8-15, live P1->P4
    Frag fcf[12];                          // waves 0-7: FC B-frags (live P1->P2)
    if (wv < 8) {
        f32x4 acc = {0.f, 0.f, 0.f, 0.f};
        #pragma unroll
        for (int kf = 0; kf < 8; ++kf) {
            Frag a;
            *(uint4*)a.u = *(const uint4*)&maskb[arow][kf * 32 + kgrp];
            acc = MFMA16(a.v, wkf[kf].v, acc);
        }
        const uint4* wsf = ws + ((size_t)(FW_FCW + wv * 12) * 64 + lane);
        #pragma unroll
        for (int kf = 0; kf < 12; ++kf) *(uint4*)fcf[kf].u = wsf[(size_t)kf * 64];
        const int n0 = 16 * wv;
        if (lane < 32) {
            #pragma unroll
            for (int j = 0; j < 4; ++j) {
                int row = (lane >> 4) * 4 + j;
                cmb[row][128 + n0 + arow] = cvt1(acc[j] * denomInv[row]);
            }
        }
    } else {
        const int w2 = wv - 8;
        Frag af[4];
        #pragma unroll
        for (int kf = 0; kf < 4; ++kf)
            *(uint4*)af[kf].u = *(const uint4*)&hf16[arow][kf * 32 + kgrp];
        const uint4* p0 = ws + ((size_t)(FW_WHH + w2 * 4) * 64 + lane);
        const uint4* p1 = ws + ((size_t)(FW_WHH + (8 + w2) * 4) * 64 + lane);
        const uint4* p2 = ws + ((size_t)(FW_WHH + (16 + w2) * 4) * 64 + lane);
        #pragma unroll
        for (int kf = 0; kf < 4; ++kf) {
            Frag b0, b1, b2;
            *(uint4*)b0.u = p0[(size_t)kf * 64];
            *(uint4*)b1.u = p1[(size_t)kf * 64];
            *(uint4*)b2.u = p2[(size_t)kf * 64];
            gh0 = MFMA16(af[kf].v, b0.v, gh0);
            gh1 = MFMA16(af[kf].v, b1.v, gh1);
            gh2 = MFMA16(af[kf].v, b2.v, gh2);
        }
    }
    __syncthreads();

    // ================ P2: FC (waves 0-7) || gi-frag prefetch (waves 8-15) ================
    Frag bfr[12];                          // waves 8-15: gi B-frags (live P2->P4)
    if (wv < 8) {
        f32x4 acc = {0.f, 0.f, 0.f, 0.f};
        #pragma unroll
        for (int kf = 0; kf < 12; ++kf) {
            Frag a;
            *(uint4*)a.u = *(const uint4*)&cmb[arow][kf * 32 + kgrp];
            acc = MFMA16(a.v, fcf[kf].v, acc);
        }
        const int n0 = 16 * wv;
        if (lane < 32) {
            #pragma unroll
            for (int j = 0; j < 4; ++j) {
                int row = (lane >> 4) * 4 + j;
                hb[row * 128 + n0 + arow] = acc[j];
            }
        }
    } else {
        const int w2 = wv - 8;
        const uint4* p0 = ws + ((size_t)(FW_WIH + w2 * 4) * 64 + lane);
        const uint4* p1 = ws + ((size_t)(FW_WIH + (8 + w2) * 4) * 64 + lane);
        const uint4* p2 = ws + ((size_t)(FW_WIH + (16 + w2) * 4) * 64 + lane);
        #pragma unroll
        for (int kf = 0; kf < 4; ++kf) {
            *(uint4*)bfr[kf].u     = p0[(size_t)kf * 64];
            *(uint4*)bfr[4 + kf].u = p1[(size_t)kf * 64];
            *(uint4*)bfr[8 + kf].u = p2[(size_t)kf * 64];
        }
    }
    __syncthreads();

    // ================ P3: LayerNorm + ReLU (waves 0-7, one row each) ================
    if (wv < 8) {
        int r = wv;
        float v0 = hb[r * 128 + lane]      + fc_b[lane];
        float v1 = hb[r * 128 + lane + 64] + fc_b[lane + 64];
        float s  = waveReduceAdd(v0 + v1);
        float ss = waveReduceAdd(v0 * v0 + v1 * v1);
        float mu   = s * (1.0f / 128.0f);
        float var  = ss * (1.0f / 128.0f) - mu * mu;
        float rstd = rsqrtf(var + 1e-5f);
        float x0 = fmaxf((v0 - mu) * rstd * ln_g[lane] + ln_b[lane], 0.f);
        float x1 = fmaxf((v1 - mu) * rstd * ln_g[lane + 64] + ln_b[lane + 64], 0.f);
        xb16[r][lane]      = cvt1(x0);
        xb16[r][lane + 64] = cvt1(x1);
    }
    __syncthreads();

    // ================ P4: gi + in-register gates (waves 8-15) || out_w prefetch (waves 0-3) ================
    Frag obf[4];                           // waves 0-3: out_w B-frags (live P4->P5)
    if (wv >= 8) {
        const int w2 = wv - 8;
        Frag af[4];
        #pragma unroll
        for (int kf = 0; kf < 4; ++kf)
            *(uint4*)af[kf].u = *(const uint4*)&xb16[arow][kf * 32 + kgrp];
        f32x4 gi0 = {0.f, 0.f, 0.f, 0.f}, gi1 = gi0, gi2 = gi0;
        #pragma unroll
        for (int kf = 0; kf < 4; ++kf) {
            gi0 = MFMA16(af[kf].v, bfr[kf].v, gi0);
            gi1 = MFMA16(af[kf].v, bfr[4 + kf].v, gi1);
            gi2 = MFMA16(af[kf].v, bfr[8 + kf].v, gi2);
        }
        if (lane < 32) {
            const int f = w2 * 16 + arow;
            float bir = b_ih[f], biz = b_ih[128 + f], bin = b_ih[256 + f];
            float bhr = b_hh[f], bhz = b_hh[128 + f], bhn = b_hh[256 + f];
            #pragma unroll
            for (int j = 0; j < 4; ++j) {
                int row = (lane >> 4) * 4 + j;
                float rg = sigm(gi0[j] + bir + gh0[j] + bhr);
                float zg = sigm(gi1[j] + biz + gh1[j] + bhz);
                float ng = tanh_fast(gi2[j] + bin + rg * (gh2[j] + bhn));
                float hprev = hf32[row * 128 + f];
                float hnew = (1.0f - zg) * ng + zg * hprev;
                hnb16[row][f] = cvt1(hnew);
                out[kOut0 + ((size_t)(b * kN + row0 + row)) * kH + f] = hnew;
            }
        }
    } else if (wv < 4) {
        const uint4* wsf = ws + ((size_t)(FW_OUTW + wv * 4) * 64 + lane);
        #pragma unroll
        for (int kf = 0; kf < 4; ++kf)
            *(uint4*)obf[kf].u = wsf[(size_t)kf * 64];
    }
    __syncthreads();

    // ================ P5: out head (waves 0-3, one 16-col tile each) ================
    if (wv < 4) {
        const int n0 = 16 * wv;
        f32x4 acc = {0.f, 0.f, 0.f, 0.f};
        #pragma unroll
        for (int kf = 0; kf < 4; ++kf) {
            Frag a;
            *(uint4*)a.u = *(const uint4*)&hnb16[arow][kf * 32 + kgrp];
            acc = MFMA16(a.v, obf[kf].v, acc);
        }
        if (lane < 32) {
            float ob = out_b[n0 + arow];
            #pragma unroll
            for (int j = 0; j < 4; ++j) {
                int row = (lane >> 4) * 4 + j;
                out[((size_t)(b * kN + row0 + row)) * kO + n0 + arow] = acc[j] + ob;
            }
        }
    }
}

} // namespace

extern "C" void kernel_launch(void* const* d_in, const int* in_sizes, int n_in,
                              void* d_out, int out_size, void* d_ws, size_t ws_size,
                              hipStream_t stream) {
    const float* lx      = (const float*)d_in[0];
    const float* gx      = (const float*)d_in[1];
    const float* mask    = (const float*)d_in[2];
    const int*   key_idx = (const int*)  d_in[3];
    const float* hs      = (const float*)d_in[4];
    const float* fc_w    = (const float*)d_in[5];
    const float* fc_b    = (const float*)d_in[6];
    const float* ln_g    = (const float*)d_in[7];
    const float* ln_b    = (const float*)d_in[8];
    const float* w_ih    = (const float*)d_in[9];
    const float* w_hh    = (const float*)d_in[10];
    const float* b_ih    = (const float*)d_in[11];
    const float* b_hh    = (const float*)d_in[12];
    const float* out_w   = (const float*)d_in[13];
    const float* out_b   = (const float*)d_in[14];
    float* out = (float*)d_out;
    uint4* ws = (uint4*)d_ws;   // needs 816 KB

    hipLaunchKernelGGL(convert_frags, dim3((FW_TOTAL * 64) / 256), dim3(256), 0, stream,
                       gx, fc_w, w_ih, w_hh, out_w, ws);

    dim3 grid(kB * kN / kR);   // 256 blocks
    dim3 block(kTPB);          // 1024 threads = 16 waves
    hipLaunchKernelGGL(weak_tie_fused, grid, block, 0, stream,
                       lx, gx, mask, key_idx, hs,
                       fc_b, ln_g, ln_b,
                       b_ih, b_hh, out_b,
                       (const uint4*)ws, out);
}